// Round 5
// baseline (468.714 us; speedup 1.0000x reference)
//
#include <hip/hip_runtime.h>
#include <hip/hip_bf16.h>

#define N_NODES 100000
#define N_EDGES 3200000
#define IN_F 256
#define OUT_F 128
#define NEG_SLOPE 0.2f
#define NB 782             // buckets of 128 rows: ceil(100000/128)
#define CHUNK 4096         // edges per mscatter block (16/thread)
#define NPB 782            // ceil(N_EDGES / CHUNK)
#define BCAP 4608          // fixed slots per 128-row bucket (mean 4096 + 8 sigma)

typedef short s16x8 __attribute__((ext_vector_type(8)));
typedef float f32x4 __attribute__((ext_vector_type(4)));
typedef float f32x2v __attribute__((ext_vector_type(2)));
typedef unsigned u32x2 __attribute__((ext_vector_type(2)));

__device__ __forceinline__ unsigned short f2bf(float f) {
    __bf16 h = (__bf16)f;
    return __builtin_bit_cast(unsigned short, h);
}
__device__ __forceinline__ float bf2f(unsigned short u) {
    unsigned int x = ((unsigned int)u) << 16;
    return __builtin_bit_cast(float, x);
}

// ---------- Kernel 0: weight fp32 -> bf16, MFMA-fragment-major layout ----------
__global__ void wcvt_kernel(const float* __restrict__ w, unsigned short* __restrict__ wb) {
    int t = blockIdx.x * blockDim.x + threadIdx.x;
    if (t >= (OUT_F / 16) * (IN_F / 32) * 64) return;   // 4096
    int lane = t & 63;
    int nt   = (t >> 6) & 7;
    int kit  = t >> 9;
    int l16  = lane & 15;
    int quad = lane >> 4;
    const float* src = w + (nt * 16 + l16) * IN_F + kit * 32 + quad * 8;
    float4 v0 = *(const float4*)src;
    float4 v1 = *(const float4*)(src + 4);
    ushort4 o0, o1;
    o0.x = f2bf(v0.x); o0.y = f2bf(v0.y); o0.z = f2bf(v0.z); o0.w = f2bf(v0.w);
    o1.x = f2bf(v1.x); o1.y = f2bf(v1.y); o1.z = f2bf(v1.z); o1.w = f2bf(v1.w);
    *(ushort4*)(wb + t * 8)     = o0;
    *(ushort4*)(wb + t * 8 + 4) = o1;
}

// ---------- Kernel 1: support = LeakyReLU(feat @ W^T) as bf16 ----------
__global__ __launch_bounds__(256) void gemm_kernel(
    const float* __restrict__ feat, const unsigned short* __restrict__ wb,
    unsigned short* __restrict__ sup) {
    int wid  = threadIdx.x >> 6;
    int lane = threadIdx.x & 63;
    long m0 = ((long)blockIdx.x * 4 + wid) * 16;
    if (m0 >= N_NODES) return;
    int quad = lane >> 4;
    int l16  = lane & 15;
    int kq   = quad * 8;

    const float* arow = feat + (m0 + l16) * IN_F + kq;

    f32x4 acc[8];
#pragma unroll
    for (int nt = 0; nt < 8; ++nt) acc[nt] = (f32x4){0.f, 0.f, 0.f, 0.f};

#pragma unroll
    for (int k0 = 0; k0 < IN_F; k0 += 32) {
        f32x4 a0 = __builtin_nontemporal_load((const f32x4*)(arow + k0));
        f32x4 a1 = __builtin_nontemporal_load((const f32x4*)(arow + k0 + 4));
        s16x8 a;
        a[0] = (short)f2bf(a0[0]); a[1] = (short)f2bf(a0[1]);
        a[2] = (short)f2bf(a0[2]); a[3] = (short)f2bf(a0[3]);
        a[4] = (short)f2bf(a1[0]); a[5] = (short)f2bf(a1[1]);
        a[6] = (short)f2bf(a1[2]); a[7] = (short)f2bf(a1[3]);
        const unsigned short* wp = wb + (k0 >> 5) * 4096 + lane * 8;
#pragma unroll
        for (int nt = 0; nt < 8; ++nt) {
            s16x8 b = *(const s16x8*)(wp + nt * 512);
            acc[nt] = __builtin_amdgcn_mfma_f32_16x16x32_bf16(a, b, acc[nt], 0, 0, 0);
        }
    }

    int crow = (int)m0 + quad * 4;
#pragma unroll
    for (int nt = 0; nt < 8; ++nt) {
#pragma unroll
        for (int r = 0; r < 4; ++r) {
            float v = acc[nt][r];
            v = (v > 0.f) ? v : (NEG_SLOPE * v);
            sup[(long)(crow + r) * OUT_F + nt * 16 + l16] = f2bf(v);
        }
    }
}

// ---------- hist: per-chunk bucket counts -> gcnt[s][b] (LDS atomics only) ----------
__global__ __launch_bounds__(256) void hist_kernel(const int* __restrict__ rows,
                                                   int* __restrict__ gcnt) {
    __shared__ int lh[NB];
    int t = threadIdx.x;
    for (int s = t; s < NB; s += 256) lh[s] = 0;
    __syncthreads();
    int e0 = blockIdx.x * CHUNK;
    int m = N_EDGES - e0; if (m > CHUNK) m = CHUNK;
    for (int k = t; k < m; k += 256)
        atomicAdd(&lh[__builtin_nontemporal_load(rows + e0 + k) >> 7], 1);
    __syncthreads();
    // column-major: scan_kernel reads bucket-rows contiguously
    for (int s = t; s < NB; s += 256)
        gcnt[s * NPB + blockIdx.x] = lh[s];
}

// ---------- scan: block per bucket; exclusive scan of its NPB chunk-counts ----------
__global__ __launch_bounds__(256) void scan_kernel(int* __restrict__ gcnt,
                                                   int* __restrict__ bcnt) {
    __shared__ int st[256];
    int s = blockIdx.x, t = threadIdx.x;
    int* row = gcnt + (long)s * NPB;
    int v[4]; int sum = 0;
#pragma unroll
    for (int k = 0; k < 4; ++k) {
        int i = t * 4 + k;
        v[k] = (i < NPB) ? row[i] : 0;
        sum += v[k];
    }
    st[t] = sum;
    __syncthreads();
    for (int o = 1; o < 256; o <<= 1) {
        int x = (t >= o) ? st[t - o] : 0;
        __syncthreads();
        st[t] += x;
        __syncthreads();
    }
    int run = st[t] - sum;
#pragma unroll
    for (int k = 0; k < 4; ++k) {
        int i = t * 4 + k;
        if (i < NPB) row[i] = run;
        run += v[k];
    }
    if (t == 255) bcnt[s] = run;   // grand total for bucket s
}

// ---------- multisplit: DIRECT register->global scatter ----------
// Exact slot = boff[bucket][chunk] + LDS-atomic rank. No stage, no sbkt,
// no block scan, no flush pass: 6.3 KB LDS -> 8 blocks/CU (was 3), and the
// serial sort chain (R3: VALUBusy 3.7%, occ 26%) collapses to 2 barriers.
// Scattered 8-B stores merge in L2 (bucket regions densely packed).
__global__ __launch_bounds__(256) void mscatter_kernel(const int* __restrict__ rows,
    const int* __restrict__ cols, const float* __restrict__ vals,
    const int* __restrict__ boff, uint2* __restrict__ ed) {
    __shared__ int lhist[NB];                   // 3128 B
    __shared__ int lbase[NB];                   // 3128 B
    int t = threadIdx.x;
    for (int s = t; s < NB; s += 256) lhist[s] = 0;
    __syncthreads();
    int e0 = blockIdx.x * CHUNK;
    int m = N_EDGES - e0; if (m > CHUNK) m = CHUNK;

    int rk[16]; int rr[16]; unsigned cw[16], vw[16];
#pragma unroll
    for (int k = 0; k < 16; ++k) {
        int i = k * 256 + t;
        if (i < m) {
            int e = e0 + i;
            int r = __builtin_nontemporal_load(rows + e);
            rr[k] = r;
            cw[k] = (unsigned)__builtin_nontemporal_load(cols + e);
            vw[k] = __builtin_bit_cast(unsigned, __builtin_nontemporal_load(vals + e));
            rk[k] = atomicAdd(&lhist[r >> 7], 1);
        }
    }
    __syncthreads();
    // exact global base per bucket for THIS chunk: plain loads, no atomics
    for (int s = t; s < NB; s += 256)
        lbase[s] = boff[(long)s * NPB + blockIdx.x];
    __syncthreads();
#pragma unroll
    for (int k = 0; k < 16; ++k) {
        int i = k * 256 + t;
        if (i < m) {
            int r  = rr[k];
            int b  = r >> 7;
            int g  = lbase[b] + rk[k];
            if (g < BCAP) {
                uint2 e;
                e.x = ((unsigned)(r & 127) << 17) | cw[k];
                e.y = vw[k];
                ed[(long)b * BCAP + g] = e;   // plain store: let L2 merge lines
            }
        }
    }
}

// ---------- gather: 512-thread block per 128-row bucket (4 blocks/CU) ----------
__global__ __launch_bounds__(512) void gather_kernel(const uint2* __restrict__ ed,
    const int* __restrict__ bcnt,
    const unsigned short* __restrict__ sup, float* __restrict__ out, int b0) {
    __shared__ uint2 stage[BCAP];   // 36864 B
    __shared__ int h[128];
    __shared__ int bs[128];
    __shared__ int cur[128];
    int t = threadIdx.x;
    int bkt = b0 + blockIdx.x;
    if (t < 128) h[t] = 0;
    __syncthreads();
    int n = bcnt[bkt]; if (n > BCAP) n = BCAP;
    const uint2* p = ed + (long)bkt * BCAP;

    // phase 1: load up to 9 edges/thread into registers (single-use stream)
    uint2 er[9];
#pragma unroll
    for (int k = 0; k < 9; ++k) {
        int i = k * 512 + t;
        if (i < n) {
            u32x2 v = __builtin_nontemporal_load((const u32x2*)(p + i));
            er[k].x = v[0]; er[k].y = v[1];
        }
    }
#pragma unroll
    for (int k = 0; k < 9; ++k) {
        int i = k * 512 + t;
        if (i < n) atomicAdd(&h[er[k].x >> 17], 1);
    }
    __syncthreads();

    // phase 2: exclusive scan of 128 counts
    if (t < 128) bs[t] = h[t];
    __syncthreads();
    for (int o = 1; o < 128; o <<= 1) {
        int v = 0;
        if (t < 128 && t >= o) v = bs[t - o];
        __syncthreads();
        if (t < 128) bs[t] += v;
        __syncthreads();
    }
    if (t < 128) {
        int excl = bs[t] - h[t];
        bs[t] = excl;
        cur[t] = excl;
    }
    __syncthreads();

    // phase 3: place edges sorted by local row
#pragma unroll
    for (int k = 0; k < 9; ++k) {
        int i = k * 512 + t;
        if (i < n) {
            int rl = er[k].x >> 17;
            int pos = atomicAdd(&cur[rl], 1);
            stage[pos] = er[k];
        }
    }
    __syncthreads();

    // phase 4: one wave per 16 rows (8 waves x 16 = 128), register accumulate
    int wid = t >> 6, lane = t & 63;
    long rowbase = (long)bkt * 128;

#define PROC(E) {                                                            \
        int col = (E).x & 0x1FFFF;                                           \
        float v = __builtin_bit_cast(float, (E).y);                          \
        ushort2 s2 = *(const ushort2*)(sup + (long)col * OUT_F + lane * 2);  \
        a0 += v * bf2f(s2.x); a1 += v * bf2f(s2.y);                          \
    }

    for (int rq = 0; rq < 16; ++rq) {
        int lr = wid * 16 + rq;
        int s0 = bs[lr];
        int mm = h[lr];
        float a0 = 0.f, a1 = 0.f;
        int i = 0;
        for (; i + 16 <= mm; i += 16) {
            uint2 e[16];
#pragma unroll
            for (int k = 0; k < 16; ++k) e[k] = stage[s0 + i + k];
#pragma unroll
            for (int k = 0; k < 16; ++k) PROC(e[k]);
        }
        for (; i + 8 <= mm; i += 8) {
            uint2 e0 = stage[s0 + i],     e1 = stage[s0 + i + 1];
            uint2 e2 = stage[s0 + i + 2], e3 = stage[s0 + i + 3];
            uint2 e4 = stage[s0 + i + 4], e5 = stage[s0 + i + 5];
            uint2 e6 = stage[s0 + i + 6], e7 = stage[s0 + i + 7];
            PROC(e0); PROC(e1); PROC(e2); PROC(e3);
            PROC(e4); PROC(e5); PROC(e6); PROC(e7);
        }
        for (; i < mm; ++i) { uint2 e0 = stage[s0 + i]; PROC(e0); }
        long grow = rowbase + lr;
        if (grow < N_NODES) {
            f32x2v f; f[0] = a0; f[1] = a1;
            __builtin_nontemporal_store(f, (f32x2v*)(out + grow * OUT_F + lane * 2));
        }
    }
#undef PROC
}

extern "C" void kernel_launch(void* const* d_in, const int* in_sizes, int n_in,
                              void* d_out, int out_size, void* d_ws, size_t ws_size,
                              hipStream_t stream) {
    const float* feat  = (const float*)d_in[0];
    const float* w     = (const float*)d_in[1];
    const float* evals = (const float*)d_in[2];
    const int*   erows = (const int*)d_in[3];
    const int*   ecols = (const int*)d_in[4];
    float* out = (float*)d_out;

    char* p = (char*)d_ws;
    unsigned short* wb  = (unsigned short*)p;  p += 65536;
    unsigned short* sup = (unsigned short*)p;  p += (size_t)N_NODES * OUT_F * 2;  // 25.6 MB
    int* gcnt   = (int*)p;                     p += (size_t)NB * NPB * 4;         // 2.45 MB
    int* bcnt   = (int*)p;                     p += 4096;
    uint2* ed   = (uint2*)p;                   // NB * BCAP * 8 = 28.8 MB

    wcvt_kernel<<<16, 256, 0, stream>>>(w, wb);

    int gemm_blocks = (N_NODES / 16 + 3) / 4;   // 1563
    gemm_kernel<<<gemm_blocks, 256, 0, stream>>>(feat, wb, sup);

    hist_kernel<<<NPB, 256, 0, stream>>>(erows, gcnt);
    scan_kernel<<<NB, 256, 0, stream>>>(gcnt, bcnt);
    mscatter_kernel<<<NPB, 256, 0, stream>>>(erows, ecols, evals, gcnt, ed);

    // gather in 4 quarters (~29 us each): instrumentation so top-5 surfaces
    // the argmax among {gemm, mscatter, quarter}; BW-bound => ~perf-neutral.
    int q = NB / 4;                  // 195
    gather_kernel<<<q, 512, 0, stream>>>(ed, bcnt, sup, out, 0);
    gather_kernel<<<q, 512, 0, stream>>>(ed, bcnt, sup, out, q);
    gather_kernel<<<q, 512, 0, stream>>>(ed, bcnt, sup, out, 2 * q);
    gather_kernel<<<NB - 3 * q, 512, 0, stream>>>(ed, bcnt, sup, out, 3 * q);
}

// Round 7
// 388.130 us; speedup vs baseline: 1.2076x; 1.2076x over previous
//
#include <hip/hip_runtime.h>
#include <hip/hip_bf16.h>

#define N_NODES 100000
#define N_EDGES 3200000
#define IN_F 256
#define OUT_F 128
#define NEG_SLOPE 0.2f
#define NB 782             // buckets of 128 rows: ceil(100000/128)
#define CHUNK 4096         // edges per mscatter block (16/thread)
#define NPB 782            // ceil(N_EDGES / CHUNK)
#define BCAP 4608          // fixed slots per 128-row bucket (mean 4096 + 8 sigma)

typedef short s16x8 __attribute__((ext_vector_type(8)));
typedef float f32x4 __attribute__((ext_vector_type(4)));
typedef float f32x2v __attribute__((ext_vector_type(2)));
typedef unsigned u32x2 __attribute__((ext_vector_type(2)));

__device__ __forceinline__ unsigned short f2bf(float f) {
    __bf16 h = (__bf16)f;
    return __builtin_bit_cast(unsigned short, h);
}
__device__ __forceinline__ float bf2f(unsigned short u) {
    unsigned int x = ((unsigned int)u) << 16;
    return __builtin_bit_cast(float, x);
}

// ---------- Kernel 0: weight fp32 -> bf16, MFMA-fragment-major layout ----------
__global__ void wcvt_kernel(const float* __restrict__ w, unsigned short* __restrict__ wb) {
    int t = blockIdx.x * blockDim.x + threadIdx.x;
    if (t >= (OUT_F / 16) * (IN_F / 32) * 64) return;   // 4096
    int lane = t & 63;
    int nt   = (t >> 6) & 7;
    int kit  = t >> 9;
    int l16  = lane & 15;
    int quad = lane >> 4;
    const float* src = w + (nt * 16 + l16) * IN_F + kit * 32 + quad * 8;
    float4 v0 = *(const float4*)src;
    float4 v1 = *(const float4*)(src + 4);
    ushort4 o0, o1;
    o0.x = f2bf(v0.x); o0.y = f2bf(v0.y); o0.z = f2bf(v0.z); o0.w = f2bf(v0.w);
    o1.x = f2bf(v1.x); o1.y = f2bf(v1.y); o1.z = f2bf(v1.z); o1.w = f2bf(v1.w);
    *(ushort4*)(wb + t * 8)     = o0;
    *(ushort4*)(wb + t * 8 + 4) = o1;
}

// ---------- Kernel 1: support = LeakyReLU(feat @ W^T) as bf16 ----------
__global__ __launch_bounds__(256) void gemm_kernel(
    const float* __restrict__ feat, const unsigned short* __restrict__ wb,
    unsigned short* __restrict__ sup) {
    int wid  = threadIdx.x >> 6;
    int lane = threadIdx.x & 63;
    long m0 = ((long)blockIdx.x * 4 + wid) * 16;
    if (m0 >= N_NODES) return;
    int quad = lane >> 4;
    int l16  = lane & 15;
    int kq   = quad * 8;

    const float* arow = feat + (m0 + l16) * IN_F + kq;

    f32x4 acc[8];
#pragma unroll
    for (int nt = 0; nt < 8; ++nt) acc[nt] = (f32x4){0.f, 0.f, 0.f, 0.f};

#pragma unroll
    for (int k0 = 0; k0 < IN_F; k0 += 32) {
        f32x4 a0 = __builtin_nontemporal_load((const f32x4*)(arow + k0));
        f32x4 a1 = __builtin_nontemporal_load((const f32x4*)(arow + k0 + 4));
        s16x8 a;
        a[0] = (short)f2bf(a0[0]); a[1] = (short)f2bf(a0[1]);
        a[2] = (short)f2bf(a0[2]); a[3] = (short)f2bf(a0[3]);
        a[4] = (short)f2bf(a1[0]); a[5] = (short)f2bf(a1[1]);
        a[6] = (short)f2bf(a1[2]); a[7] = (short)f2bf(a1[3]);
        const unsigned short* wp = wb + (k0 >> 5) * 4096 + lane * 8;
#pragma unroll
        for (int nt = 0; nt < 8; ++nt) {
            s16x8 b = *(const s16x8*)(wp + nt * 512);
            acc[nt] = __builtin_amdgcn_mfma_f32_16x16x32_bf16(a, b, acc[nt], 0, 0, 0);
        }
    }

    int crow = (int)m0 + quad * 4;
#pragma unroll
    for (int nt = 0; nt < 8; ++nt) {
#pragma unroll
        for (int r = 0; r < 4; ++r) {
            float v = acc[nt][r];
            v = (v > 0.f) ? v : (NEG_SLOPE * v);
            sup[(long)(crow + r) * OUT_F + nt * 16 + l16] = f2bf(v);
        }
    }
}

// ---------- hist: per-chunk bucket counts -> gcnt[s][b] (LDS atomics only) ----------
__global__ __launch_bounds__(256) void hist_kernel(const int* __restrict__ rows,
                                                   int* __restrict__ gcnt) {
    __shared__ int lh[NB];
    int t = threadIdx.x;
    for (int s = t; s < NB; s += 256) lh[s] = 0;
    __syncthreads();
    int e0 = blockIdx.x * CHUNK;
    int m = N_EDGES - e0; if (m > CHUNK) m = CHUNK;
    for (int k = t; k < m; k += 256)
        atomicAdd(&lh[__builtin_nontemporal_load(rows + e0 + k) >> 7], 1);
    __syncthreads();
    // column-major: scan_kernel reads bucket-rows contiguously
    for (int s = t; s < NB; s += 256)
        gcnt[s * NPB + blockIdx.x] = lh[s];
}

// ---------- scan: block per bucket; exclusive scan of its NPB chunk-counts ----------
__global__ __launch_bounds__(256) void scan_kernel(int* __restrict__ gcnt,
                                                   int* __restrict__ bcnt) {
    __shared__ int st[256];
    int s = blockIdx.x, t = threadIdx.x;
    int* row = gcnt + (long)s * NPB;
    int v[4]; int sum = 0;
#pragma unroll
    for (int k = 0; k < 4; ++k) {
        int i = t * 4 + k;
        v[k] = (i < NPB) ? row[i] : 0;
        sum += v[k];
    }
    st[t] = sum;
    __syncthreads();
    for (int o = 1; o < 256; o <<= 1) {
        int x = (t >= o) ? st[t - o] : 0;
        __syncthreads();
        st[t] += x;
        __syncthreads();
    }
    int run = st[t] - sum;
#pragma unroll
    for (int k = 0; k < 4; ++k) {
        int i = t * 4 + k;
        if (i < NPB) row[i] = run;
        run += v[k];
    }
    if (t == 255) bcnt[s] = run;   // grand total for bucket s
}

// ---------- multisplit (R4 staged version, proven <66 us) ----------
// ed entry: x = (row_local<<17) | col, y = val bits. ZERO global atomics:
// exact write bases come from the scanned gcnt matrix; block-local counting
// sort keeps the flush run-coalesced (avg run ~5.2 edges).
__global__ __launch_bounds__(256) void mscatter_kernel(const int* __restrict__ rows,
    const int* __restrict__ cols, const float* __restrict__ vals,
    const int* __restrict__ boff, uint2* __restrict__ ed) {
    __shared__ uint2 stage[CHUNK];              // 32768 B
    __shared__ unsigned short sbkt[CHUNK];      // 8192 B
    __shared__ int lhist[NB];                   // 3128 B
    __shared__ int lbase[NB];                   // 3128 B
    __shared__ int st[256];                     // 1024 B   => 48.2 KB total
    int t = threadIdx.x;
    for (int s = t; s < NB; s += 256) lhist[s] = 0;
    __syncthreads();
    int e0 = blockIdx.x * CHUNK;
    int m = N_EDGES - e0; if (m > CHUNK) m = CHUNK;

    int rk[16]; int rr[16]; unsigned cw[16], vw[16];
#pragma unroll
    for (int k = 0; k < 16; ++k) {
        int i = k * 256 + t;
        if (i < m) {
            int e = e0 + i;
            int r = __builtin_nontemporal_load(rows + e);
            rr[k] = r;
            cw[k] = (unsigned)__builtin_nontemporal_load(cols + e);
            vw[k] = __builtin_bit_cast(unsigned, __builtin_nontemporal_load(vals + e));
            rk[k] = atomicAdd(&lhist[r >> 7], 1);
        }
    }
    __syncthreads();
    // exact global base per bucket for THIS chunk: plain loads, no atomics
    for (int s = t; s < NB; s += 256)
        lbase[s] = boff[(long)s * NPB + blockIdx.x];
    // in-place exclusive scan of lhist (counts snapshotted into hv)
    int base = t * 4; int sum = 0; int hv[4];
#pragma unroll
    for (int k = 0; k < 4; ++k) {
        int s = base + k;
        hv[k] = (s < NB) ? lhist[s] : 0;
        sum += hv[k];
    }
    st[t] = sum;
    __syncthreads();
    for (int o = 1; o < 256; o <<= 1) {
        int x = (t >= o) ? st[t - o] : 0;
        __syncthreads();
        st[t] += x;
        __syncthreads();
    }
    int run = st[t] - sum;
#pragma unroll
    for (int k = 0; k < 4; ++k) {
        int s = base + k;
        if (s < NB) lhist[s] = run;
        run += hv[k];
    }
    __syncthreads();
#pragma unroll
    for (int k = 0; k < 16; ++k) {
        int i = k * 256 + t;
        if (i < m) {
            int r  = rr[k];
            int b  = r >> 7;
            int rl = r & 127;
            int pos = lhist[b] + rk[k];
            stage[pos].x = ((unsigned)rl << 17) | cw[k];
            stage[pos].y = vw[k];
            sbkt[pos] = (unsigned short)b;
        }
    }
    __syncthreads();
    for (int i = t; i < m; i += 256) {
        int b = sbkt[i];
        int g = lbase[b] + (i - lhist[b]);
        if (g < BCAP) ed[(long)b * BCAP + g] = stage[i];
    }
}

// ---------- gather: ONE dispatch, 782 blocks x 512 threads, full bucket ----------
// 38.4 KB LDS -> 4 blocks/CU (32 waves/CU); ed read exactly once.
__global__ __launch_bounds__(512) void gather_kernel(const uint2* __restrict__ ed,
    const int* __restrict__ bcnt,
    const unsigned short* __restrict__ sup, float* __restrict__ out) {
    __shared__ uint2 stage[BCAP];   // 36864 B
    __shared__ int h[128];
    __shared__ int bs[128];
    __shared__ int cur[128];
    int t = threadIdx.x;
    int bkt = blockIdx.x;
    if (t < 128) h[t] = 0;
    __syncthreads();
    int n = bcnt[bkt]; if (n > BCAP) n = BCAP;
    const uint2* p = ed + (long)bkt * BCAP;

    // phase 1: load up to 9 edges/thread into registers (single-use stream)
    uint2 er[9];
#pragma unroll
    for (int k = 0; k < 9; ++k) {
        int i = k * 512 + t;
        if (i < n) {
            u32x2 v = __builtin_nontemporal_load((const u32x2*)(p + i));
            er[k].x = v[0]; er[k].y = v[1];
        }
    }
#pragma unroll
    for (int k = 0; k < 9; ++k) {
        int i = k * 512 + t;
        if (i < n) atomicAdd(&h[er[k].x >> 17], 1);
    }
    __syncthreads();

    // phase 2: exclusive scan of 128 counts
    if (t < 128) bs[t] = h[t];
    __syncthreads();
    for (int o = 1; o < 128; o <<= 1) {
        int v = 0;
        if (t < 128 && t >= o) v = bs[t - o];
        __syncthreads();
        if (t < 128) bs[t] += v;
        __syncthreads();
    }
    if (t < 128) {
        int excl = bs[t] - h[t];
        bs[t] = excl;
        cur[t] = excl;
    }
    __syncthreads();

    // phase 3: place edges sorted by local row
#pragma unroll
    for (int k = 0; k < 9; ++k) {
        int i = k * 512 + t;
        if (i < n) {
            int rl = er[k].x >> 17;
            int pos = atomicAdd(&cur[rl], 1);
            stage[pos] = er[k];
        }
    }
    __syncthreads();

    // phase 4: one wave per 16 rows (8 waves x 16 = 128), register accumulate
    int wid = t >> 6, lane = t & 63;
    long rowbase = (long)bkt * 128;

#define PROC(E) {                                                            \
        int col = (E).x & 0x1FFFF;                                           \
        float v = __builtin_bit_cast(float, (E).y);                          \
        ushort2 s2 = *(const ushort2*)(sup + (long)col * OUT_F + lane * 2);  \
        a0 += v * bf2f(s2.x); a1 += v * bf2f(s2.y);                          \
    }

    for (int rq = 0; rq < 16; ++rq) {
        int lr = wid * 16 + rq;
        int s0 = bs[lr];
        int mm = h[lr];
        float a0 = 0.f, a1 = 0.f;
        int i = 0;
        for (; i + 16 <= mm; i += 16) {
            uint2 e[16];
#pragma unroll
            for (int k = 0; k < 16; ++k) e[k] = stage[s0 + i + k];
#pragma unroll
            for (int k = 0; k < 16; ++k) PROC(e[k]);
        }
        for (; i + 8 <= mm; i += 8) {
            uint2 e0 = stage[s0 + i],     e1 = stage[s0 + i + 1];
            uint2 e2 = stage[s0 + i + 2], e3 = stage[s0 + i + 3];
            uint2 e4 = stage[s0 + i + 4], e5 = stage[s0 + i + 5];
            uint2 e6 = stage[s0 + i + 6], e7 = stage[s0 + i + 7];
            PROC(e0); PROC(e1); PROC(e2); PROC(e3);
            PROC(e4); PROC(e5); PROC(e6); PROC(e7);
        }
        for (; i < mm; ++i) { uint2 e0 = stage[s0 + i]; PROC(e0); }
        long grow = rowbase + lr;
        if (grow < N_NODES) {
            f32x2v f; f[0] = a0; f[1] = a1;
            __builtin_nontemporal_store(f, (f32x2v*)(out + grow * OUT_F + lane * 2));
        }
    }
#undef PROC
}

extern "C" void kernel_launch(void* const* d_in, const int* in_sizes, int n_in,
                              void* d_out, int out_size, void* d_ws, size_t ws_size,
                              hipStream_t stream) {
    const float* feat  = (const float*)d_in[0];
    const float* w     = (const float*)d_in[1];
    const float* evals = (const float*)d_in[2];
    const int*   erows = (const int*)d_in[3];
    const int*   ecols = (const int*)d_in[4];
    float* out = (float*)d_out;

    char* p = (char*)d_ws;
    unsigned short* wb  = (unsigned short*)p;  p += 65536;
    unsigned short* sup = (unsigned short*)p;  p += (size_t)N_NODES * OUT_F * 2;  // 25.6 MB
    int* gcnt   = (int*)p;                     p += (size_t)NB * NPB * 4;         // 2.45 MB
    int* bcnt   = (int*)p;                     p += 4096;
    uint2* ed   = (uint2*)p;                   // NB * BCAP * 8 = 28.8 MB

    wcvt_kernel<<<16, 256, 0, stream>>>(w, wb);

    int gemm_blocks = (N_NODES / 16 + 3) / 4;   // 1563
    gemm_kernel<<<gemm_blocks, 256, 0, stream>>>(feat, wb, sup);

    hist_kernel<<<NPB, 256, 0, stream>>>(erows, gcnt);
    scan_kernel<<<NB, 256, 0, stream>>>(gcnt, bcnt);
    mscatter_kernel<<<NPB, 256, 0, stream>>>(erows, ecols, evals, gcnt, ed);

    // single dispatch: 782 blocks, ~3-4 blocks/CU — no tail-bound sub-dispatches
    gather_kernel<<<NB, 512, 0, stream>>>(ed, bcnt, sup, out);
}